// Round 6
// baseline (296.139 us; speedup 1.0000x reference)
//
#include <hip/hip_runtime.h>
#include <hip/hip_cooperative_groups.h>
#include <math.h>

namespace cg = cooperative_groups;

#define NB 8
#define NA 512
#define NN 64
#define ND 128
#define NF 128
#define NG 25
#define NGA 512
#define TABN 1024

typedef __attribute__((ext_vector_type(8))) short bf16x8;
typedef __attribute__((ext_vector_type(4))) float f32x4;

__device__ __forceinline__ float sspf(float v) {
  return fmaxf(v, 0.0f) + __logf(1.0f + __expf(-fabsf(v))) - 0.6931471805599453f;
}

__device__ __forceinline__ short f2bf(float x) {
  union { float f; unsigned u; } v; v.f = x;
  unsigned r = v.u + 0x7fffu + ((v.u >> 16) & 1u);   // RNE
  return (short)(r >> 16);
}

#if defined(__has_builtin)
#if __has_builtin(__builtin_amdgcn_cvt_pk_bf16_f32)
#define HAS_PKBF 1
#endif
#endif

__device__ __forceinline__ unsigned pk2bf(float a, float b) {
#ifdef HAS_PKBF
  typedef __attribute__((ext_vector_type(2))) __bf16 v2bf;
  union { v2bf v; unsigned u; } c;
  c.v = __builtin_amdgcn_cvt_pk_bf16_f32(a, b);
  return c.u;
#else
  union { float f; unsigned u; } x, y; x.f = a; y.f = b;
  const unsigned ra = (x.u + 0x7fffu + ((x.u >> 16) & 1u)) >> 16;
  const unsigned rb = (y.u + 0x7fffu + ((y.u >> 16) & 1u)) & 0xffff0000u;
  return ra | rb;
#endif
}

__device__ __forceinline__ float bf2f(unsigned short us) {
  union { unsigned u; float f; } v; v.u = ((unsigned)us) << 16; return v.f;
}

__device__ __forceinline__ bf16x8 pack8(float4 a, float4 b) {
  bf16x8 r;
  unsigned* p = (unsigned*)&r;
  p[0] = pk2bf(a.x, a.y); p[1] = pk2bf(a.z, a.w);
  p[2] = pk2bf(b.x, b.y); p[3] = pk2bf(b.z, b.w);
  return r;
}

// W^T-style fragment built from row-major M[k][n]: elem i = bf16(M[k0q+i][n])
__device__ __forceinline__ bf16x8 fragT(const float* __restrict__ M, int ldn,
                                        int n, int k0q) {
  float e[8];
#pragma unroll
  for (int i = 0; i < 8; ++i) e[i] = M[(size_t)(k0q + i) * ldn + n];
  bf16x8 r; unsigned* p = (unsigned*)&r;
  p[0] = pk2bf(e[0], e[1]); p[1] = pk2bf(e[2], e[3]);
  p[2] = pk2bf(e[4], e[5]); p[3] = pk2bf(e[6], e[7]);
  return r;
}

struct KP {
  const int* zn; const float* pos; const int* nbr; const int* nmask;
  const float* Gi; const float* emb;
  const float* fw1; const float* fb1; const float* fw2; const float* fb2;
  const float* in2f; const float* f2o; const float* f2ob;
  const float* dw; const float* db; const float* aw;
  float* x; float* b12; float* Ttab;
  short* yA; short* yBb; short* in2fT; short* W12T; short* awT;
  short* w1T; short* w2T;
};

// vb task ranges in phase 0 (each task = 256 threads)
#define T_TT 96                  // fw2,in2f transposes
#define T_AT (T_TT + 192)        // aw transpose -> 288
#define T_W1 (T_AT + 48)         // w1T pad-transpose -> 336
#define T_PF (T_W1 + 24)         // W12 fuse + b12 -> 360

__global__ __launch_bounds__(512, 1) void k_all(KP p) {
  __shared__ alignas(16) short sTile[2][32][33];
  __shared__ alignas(16) float sB12[3][2][128];
  __shared__ alignas(16) short sH[16 * 136];
  __shared__ alignas(16) float2 sA[8][2][NN];
  __shared__ alignas(16) int2 sM[8][2][NN];
  __shared__ alignas(16) float sAgg[16][136];
  __shared__ alignas(16) short sT[16 * 136];
  __shared__ alignas(16) short sVang[3][16][132];

  cg::grid_group grid = cg::this_grid();

  const int t = threadIdx.x;
  const int bx = blockIdx.x;

  // ================= phase 0: prep tasks (2 virtual 256-thr tasks/block) ====
  {
    const int vb = (bx << 1) | (t >> 8);
    const int vt = t & 255;
    const int half = t >> 8;

    short* finDst = nullptr;
    int finStride = 0, finTr = 0, finTc4 = 0, finTk0 = 0, finTn0 = 0;

    if (vb < T_AT) {
      // ---- tiled bf16 transposes ----
      const float* src; short* dst; int tk0, tn0, stride;
      if (vb < T_TT) {
        const int mat = vb >> 4, tile = vb & 15;
        const int l = mat >> 1, which = mat & 1;
        src = (which ? p.in2f : p.fw2) + (size_t)l * 16384;
        dst = (which ? p.in2fT : p.w2T) + (size_t)l * 16384;
        tk0 = (tile >> 2) << 5; tn0 = (tile & 3) << 5; stride = 128;
      } else {
        const int ab = vb - T_TT;
        const int l = ab >> 6, tile = ab & 63;
        src = p.aw + (size_t)l * 65536;
        dst = p.awT + (size_t)l * 65536;
        tk0 = (tile >> 2) << 5; tn0 = (tile & 3) << 5; stride = 512;
      }
      const int tr = vt >> 3, tc4 = (vt & 7) << 2;
      const float4 v = *(const float4*)(src + (size_t)(tk0 + tr) * 128 + tn0 + tc4);
      sTile[half][tr][tc4] = f2bf(v.x); sTile[half][tr][tc4 + 1] = f2bf(v.y);
      sTile[half][tr][tc4 + 2] = f2bf(v.z); sTile[half][tr][tc4 + 3] = f2bf(v.w);
      finDst = dst; finStride = stride; finTr = tr; finTc4 = tc4;
      finTk0 = tk0; finTn0 = tn0;
    } else if (vb < T_W1) {
      // ---- w1T[l][n][k] (k padded 25->32) ----
      const int idx = (vb - T_AT) * 256 + vt;
      const int l = idx >> 12, r = idx & 4095, n = r >> 5, k = r & 31;
      p.w1T[idx] = (k < NG) ? f2bf(p.fw1[(size_t)l * NG * NF + k * NF + n]) : (short)0;
    } else if (vb < T_PF) {
      // ---- W12 = f2o@dw (bf16 [j][i]); b12 partials ----
      const int fbk = vb - T_W1;
      const int l = fbk >> 3, xi = fbk & 7;
      const int lane_v = vt & 63, wave_v = vt >> 6;
      const int llo = lane_v & 15, qd = lane_v >> 4;
      const int wb = wave_v << 5;
      const int i = (xi << 4) + llo;
      const float* f2o_l = p.f2o + (size_t)l * 16384;
      const float* dw_l = p.dw + (size_t)l * 16384;
      short* W12T_l = p.W12T + (size_t)l * 16384;
      f32x4 c[2] = {{0.f, 0.f, 0.f, 0.f}, {0.f, 0.f, 0.f, 0.f}};
#pragma unroll
      for (int kt = 0; kt < 4; ++kt) {
        const int k0 = kt * 32 + qd * 8;
        const bf16x8 b = pack8(*(const float4*)(f2o_l + (size_t)i * 128 + k0),
                               *(const float4*)(f2o_l + (size_t)i * 128 + k0 + 4));
#pragma unroll
        for (int ct = 0; ct < 2; ++ct) {
          const bf16x8 a = fragT(dw_l, 128, wb + ct * 16 + llo, k0);
          c[ct] = __builtin_amdgcn_mfma_f32_16x16x32_bf16(a, b, c[ct], 0, 0, 0);
        }
      }
#pragma unroll
      for (int ct = 0; ct < 2; ++ct)
#pragma unroll
        for (int reg = 0; reg < 4; ++reg) {
          const int j = wb + ct * 16 + qd * 4 + reg;
          W12T_l[(size_t)j * 128 + i] = f2bf(c[ct][reg]);
        }
      if (xi == 0) {
        const int j = vt & 127, hf = vt >> 7;
        const float* f2ob_l = p.f2ob + (size_t)l * 128;
        const float* dwc = dw_l + j;
        float a0 = 0.f, a1 = 0.f, a2 = 0.f, a3 = 0.f;
        const int kb = hf * 64;
        for (int k = kb; k < kb + 64; k += 4) {
          a0 = fmaf(f2ob_l[k], dwc[(size_t)k * 128], a0);
          a1 = fmaf(f2ob_l[k + 1], dwc[(size_t)(k + 1) * 128], a1);
          a2 = fmaf(f2ob_l[k + 2], dwc[(size_t)(k + 2) * 128], a2);
          a3 = fmaf(f2ob_l[k + 3], dwc[(size_t)(k + 3) * 128], a3);
        }
        sB12[l][hf][j] = a0 + a1 + a2 + a3;
      }
    }
    __syncthreads();
    if (finDst) {
      short o[4];
#pragma unroll
      for (int j = 0; j < 4; ++j) o[j] = sTile[half][finTc4 + j][finTr];
      uint2 pk;
      pk.x = ((unsigned)(unsigned short)o[0]) | (((unsigned)(unsigned short)o[1]) << 16);
      pk.y = ((unsigned)(unsigned short)o[2]) | (((unsigned)(unsigned short)o[3]) << 16);
      *(uint2*)(finDst + (size_t)(finTn0 + finTr) * finStride + finTk0 + finTc4) = pk;
    }
    if (vb >= T_W1 && vb < T_PF) {
      const int fbk = vb - T_W1;
      const int l = fbk >> 3, xi = fbk & 7;
      if (xi == 0 && vt < 128)
        p.b12[(size_t)l * 128 + vt] =
            p.db[(size_t)l * 128 + vt] + sB12[l][0][vt] + sB12[l][1][vt];
    }
  }
  grid.sync();

  // ================= phase A: table + vang(own atoms) + y0 =================
  const int lane = t & 63;
  const int wave = t >> 6;          // 0..7
  const int lanelo = lane & 15;
  const int quad = lane >> 4;
  const int ga0 = bx << 4;
  const int b0 = ga0 & ~(NA - 1);

  if (bx < 192) {
    // ---- filter table chunk: l = bx>>6, rows chunk*16..+15 (8 waves x 16 cols)
    const int l = bx >> 6;
    const int chunk = bx & 63;
    const short* w1Tl = p.w1T + (size_t)l * 128 * 32;
    const short* w2Tl = p.w2T + (size_t)l * 16384;
    const float* b1 = p.fb1 + (size_t)l * NF;
    const float* b2 = p.fb2 + (size_t)l * NF;
    const int n = (wave << 4) + lanelo;

    const bf16x8 bw1 = *(const bf16x8*)(w1Tl + n * 32 + quad * 8);
    bf16x8 bw2[4];
#pragma unroll
    for (int kt = 0; kt < 4; ++kt)
      bw2[kt] = *(const bf16x8*)(w2Tl + n * 128 + kt * 32 + quad * 8);
    const float4 b1v = *(const float4*)(b1 + (wave << 4) + quad * 4);
    const float b2r = b2[n];

    const float stepg = 3.8f / 24.0f;
    const float coef = -0.5f / (stepg * stepg);
    const float rv = (float)(chunk * 16 + lanelo) * (5.0f / 1023.0f);
    bf16x8 gb;
    {
      float e[8];
#pragma unroll
      for (int i = 0; i < 8; ++i) {
        const int g = quad * 8 + i;
        const float d = rv - (1.2f + stepg * (float)g);
        e[i] = (g < NG) ? __expf(coef * d * d) : 0.0f;
      }
      unsigned* gp = (unsigned*)&gb;
      gp[0] = pk2bf(e[0], e[1]); gp[1] = pk2bf(e[2], e[3]);
      gp[2] = pk2bf(e[4], e[5]); gp[3] = pk2bf(e[6], e[7]);
    }
    // phase 1: h = ssp(gauss @ w1 + b1)
    {
      f32x4 c = {0.f, 0.f, 0.f, 0.f};
      c = __builtin_amdgcn_mfma_f32_16x16x32_bf16(bw1, gb, c, 0, 0, 0);
      const int f0 = (wave << 4) + quad * 4;
      uint2 pk;
      pk.x = pk2bf(sspf(c[0] + b1v.x), sspf(c[1] + b1v.y));
      pk.y = pk2bf(sspf(c[2] + b1v.z), sspf(c[3] + b1v.w));
      *(uint2*)(sH + lanelo * 136 + f0) = pk;
    }
    __syncthreads();
    // phase 2: T = h @ w2 + b2 -> Ttab fp32
    f32x4 acc = {b2r, b2r, b2r, b2r};
#pragma unroll
    for (int kt = 0; kt < 4; ++kt) {
      const bf16x8 ah = *(const bf16x8*)(sH + lanelo * 136 + kt * 32 + quad * 8);
      acc = __builtin_amdgcn_mfma_f32_16x16x32_bf16(ah, bw2[kt], acc, 0, 0, 0);
    }
#pragma unroll
    for (int reg = 0; reg < 4; ++reg) {
      const int rrow = chunk * 16 + quad * 4 + reg;
      p.Ttab[((size_t)l * TABN + rrow) * NF + n] = acc[reg];
    }
  }

  // ---- vang for own 16 atoms, 3 layers, into LDS sVang ----
  {
    f32x4 acc[3] = {{0.f, 0.f, 0.f, 0.f}, {0.f, 0.f, 0.f, 0.f}, {0.f, 0.f, 0.f, 0.f}};
    const int n = (wave << 4) + lanelo;
    const float* grow = p.Gi + (size_t)(ga0 + lanelo) * NGA;
#pragma unroll
    for (int kt = 0; kt < 16; ++kt) {
      const int k0 = kt * 32 + quad * 8;
      const bf16x8 b = pack8(*(const float4*)(grow + k0),
                             *(const float4*)(grow + k0 + 4));
#pragma unroll
      for (int l = 0; l < 3; ++l) {
        const bf16x8 a = *(const bf16x8*)(p.awT + (size_t)l * 65536 + (size_t)n * 512 + k0);
        acc[l] = __builtin_amdgcn_mfma_f32_16x16x32_bf16(a, b, acc[l], 0, 0, 0);
      }
    }
#pragma unroll
    for (int l = 0; l < 3; ++l) {
      uint2 pk; pk.x = pk2bf(acc[l][0], acc[l][1]); pk.y = pk2bf(acc[l][2], acc[l][3]);
      *(uint2*)&sVang[l][lanelo][(wave << 4) + quad * 4] = pk;
    }
  }

  // ---- y0 = bf16(emb[zn] @ in2f[0]); wave 0 writes x = emb[zn] ----
  {
    const int row = ga0 + lanelo;
    const float* erow = p.emb + (size_t)p.zn[row] * ND;
    const int n = (wave << 4) + lanelo;
    f32x4 c = {0.f, 0.f, 0.f, 0.f};
#pragma unroll
    for (int kt = 0; kt < 4; ++kt) {
      const int k0 = kt * 32 + quad * 8;
      const float4 e0 = *(const float4*)(erow + k0);
      const float4 e1 = *(const float4*)(erow + k0 + 4);
      if (wave == 0) {
        *(float4*)(p.x + (size_t)row * ND + k0) = e0;
        *(float4*)(p.x + (size_t)row * ND + k0 + 4) = e1;
      }
      const bf16x8 b = pack8(e0, e1);
      const bf16x8 a = *(const bf16x8*)(p.in2fT + (size_t)n * 128 + k0);
      c = __builtin_amdgcn_mfma_f32_16x16x32_bf16(a, b, c, 0, 0, 0);
    }
    uint2 pk; pk.x = pk2bf(c[0], c[1]); pk.y = pk2bf(c[2], c[3]);
    *(uint2*)(p.yA + (size_t)row * 128 + (wave << 4) + quad * 4) = pk;
  }
  grid.sync();

  // ================= layers 0..2: table-lerp conv + update ==================
  const short* yin = p.yA;
  short* yout = p.yBb;
  for (int l = 0; l < 3; ++l) {
    const float* Tt = p.Ttab + (size_t)l * TABN * NF;
    const short* W12Tl = p.W12T + (size_t)l * 16384;
    const float* b12l = p.b12 + (size_t)l * 128;

    // ---- per-wave: 2 atoms, ballot compaction ----
    int nvv[2];
#pragma unroll
    for (int aa = 0; aa < 2; ++aa) {
      const int ga = ga0 + (wave << 1) + aa;
      sA[wave][aa][lane] = make_float2(0.f, 0.f);
      sM[wave][aa][lane] = make_int2(0, b0 * NF);
      const int nj = p.nbr[(size_t)ga * NN + lane];
      const int mk = p.nmask[(size_t)ga * NN + lane];
      const float px = p.pos[(size_t)ga * 3];
      const float py = p.pos[(size_t)ga * 3 + 1];
      const float pz = p.pos[(size_t)ga * 3 + 2];
      const float* pj = p.pos + (size_t)(b0 + nj) * 3;
      const float dx = pj[0] - px, dy = pj[1] - py, dz = pj[2] - pz;
      const float r = sqrtf(dx * dx + dy * dy + dz * dz + 1e-12f);
      const bool valid = (r <= 5.0f) && (mk != 0);
      const unsigned long long m = __ballot(valid);
      const int posc = __popcll(m & ((1ull << lane) - 1ull));
      const float tt = r * ((float)(TABN - 1) / 5.0f);
      int k0 = (int)tt; if (k0 > TABN - 2) k0 = TABN - 2;
      const float fr = tt - (float)k0;
      if (valid) {
        sA[wave][aa][posc] = make_float2(1.0f - fr, fr);
        sM[wave][aa][posc] = make_int2(k0 * NF, (b0 + nj) * NF);
      }
      nvv[aa] = (int)__popcll(m);
    }

    const unsigned short* yu = (const unsigned short*)yin;
#pragma unroll
    for (int aa = 0; aa < 2; ++aa) {
      float acc0 = 0.f, acc1 = 0.f;
      const int ntc = (nvv[aa] + 3) & ~3;
      for (int c = 0; c < ntc; c += 4) {
#pragma unroll
        for (int u = 0; u < 4; ++u) {
          const float2 w = sA[wave][aa][c + u];
          const int2 off = sM[wave][aa][c + u];
          const float t0a = Tt[off.x + lane];
          const float t0b = Tt[off.x + lane + 64];
          const float t1a = Tt[off.x + NF + lane];
          const float t1b = Tt[off.x + NF + lane + 64];
          const float wva = fmaf(w.x, t0a, w.y * t1a);
          const float wvb = fmaf(w.x, t0b, w.y * t1b);
          acc0 = fmaf(wva, bf2f(yu[off.y + lane]), acc0);
          acc1 = fmaf(wvb, bf2f(yu[off.y + lane + 64]), acc1);
        }
      }
      const int al = (wave << 1) + aa;
      sAgg[al][lane] = acc0;
      sAgg[al][lane + 64] = acc1;
    }
    __syncthreads();

    // ---- update GEMM 1: v2 = W12 @ agg ----
    f32x4 c2 = {0.f, 0.f, 0.f, 0.f};
#pragma unroll
    for (int kt = 0; kt < 4; ++kt) {
      const float* ar = &sAgg[lanelo][kt * 32 + quad * 8];
      const bf16x8 b = pack8(*(const float4*)ar, *(const float4*)(ar + 4));
      const bf16x8 a = *(const bf16x8*)(W12Tl + ((wave << 4) + lanelo) * 128 + kt * 32 + quad * 8);
      c2 = __builtin_amdgcn_mfma_f32_16x16x32_bf16(a, b, c2, 0, 0, 0);
    }

    const int c0 = (wave << 4) + quad * 4;
    const int row = ga0 + lanelo;
    {
      const float4 dv = *(const float4*)(b12l + c0);
      const unsigned short* vp = (const unsigned short*)&sVang[l][lanelo][c0];
      float* xp = p.x + (size_t)row * 128 + c0;
      const float4 xv = *(const float4*)xp;
      float4 xo;
      xo.x = xv.x + sspf(c2[0] + bf2f(vp[0]) + dv.x);
      xo.y = xv.y + sspf(c2[1] + bf2f(vp[1]) + dv.y);
      xo.z = xv.z + sspf(c2[2] + bf2f(vp[2]) + dv.z);
      xo.w = xv.w + sspf(c2[3] + bf2f(vp[3]) + dv.w);
      *(float4*)xp = xo;
      if (l < 2) {
        uint2 pk; pk.x = pk2bf(xo.x, xo.y); pk.y = pk2bf(xo.z, xo.w);
        *(uint2*)(sT + lanelo * 136 + c0) = pk;
      }
    }
    if (l < 2) {
      __syncthreads();
      // ---- update GEMM 2: y_next = in2f[l+1] @ x_new ----
      const short* in2fTn = p.in2fT + (size_t)(l + 1) * 16384;
      f32x4 c3 = {0.f, 0.f, 0.f, 0.f};
#pragma unroll
      for (int kt = 0; kt < 4; ++kt) {
        const bf16x8 b = *(const bf16x8*)(sT + lanelo * 136 + kt * 32 + quad * 8);
        const bf16x8 a = *(const bf16x8*)(in2fTn + ((wave << 4) + lanelo) * 128 + kt * 32 + quad * 8);
        c3 = __builtin_amdgcn_mfma_f32_16x16x32_bf16(a, b, c3, 0, 0, 0);
      }
      uint2 pk; pk.x = pk2bf(c3[0], c3[1]); pk.y = pk2bf(c3[2], c3[3]);
      *(uint2*)(yout + (size_t)row * 128 + c0) = pk;

      grid.sync();
      const short* tmp = yin; yin = yout; yout = (short*)tmp;
    }
  }
}

extern "C" void kernel_launch(void* const* d_in, const int* in_sizes, int n_in,
                              void* d_out, int out_size, void* d_ws, size_t ws_size,
                              hipStream_t stream) {
  (void)in_sizes; (void)n_in; (void)out_size; (void)ws_size;
  KP prm;
  prm.zn = (const int*)d_in[0];
  prm.pos = (const float*)d_in[1];
  prm.nbr = (const int*)d_in[2];
  prm.nmask = (const int*)d_in[3];
  prm.Gi = (const float*)d_in[4];
  prm.emb = (const float*)d_in[5];
  prm.fw1 = (const float*)d_in[6];
  prm.fb1 = (const float*)d_in[7];
  prm.fw2 = (const float*)d_in[8];
  prm.fb2 = (const float*)d_in[9];
  prm.in2f = (const float*)d_in[10];
  prm.f2o = (const float*)d_in[11];
  prm.f2ob = (const float*)d_in[12];
  prm.dw = (const float*)d_in[13];
  prm.db = (const float*)d_in[14];
  prm.aw = (const float*)d_in[15];

  prm.x = (float*)d_out;
  float* ws = (float*)d_ws;
  prm.b12 = ws;                                     // 3*128 fp32
  prm.Ttab = ws + 3 * 128;                          // 3*1024*128 fp32
  short* s = (short*)(prm.Ttab + (size_t)3 * TABN * NF);
  prm.yA = s;            s += (size_t)NB * NA * NF; // bf16 y buf 0
  prm.yBb = s;           s += (size_t)NB * NA * NF; // bf16 y buf 1
  prm.in2fT = s;         s += (size_t)3 * 128 * 128;
  prm.W12T = s;          s += (size_t)3 * 128 * 128;
  prm.awT = s;           s += (size_t)3 * 128 * 512;
  prm.w1T = s;           s += (size_t)3 * 128 * 32;
  prm.w2T = s;

  void* args[] = { (void*)&prm };
  hipLaunchCooperativeKernel((const void*)k_all, dim3(256), dim3(512), args, 0, stream);
}

// Round 7
// 149.668 us; speedup vs baseline: 1.9786x; 1.9786x over previous
//
#include <hip/hip_runtime.h>
#include <math.h>

#define NB 8
#define NA 512
#define NN 64
#define ND 128
#define NF 128
#define NG 25
#define NGA 512
#define TABN 1024

typedef __attribute__((ext_vector_type(8))) short bf16x8;
typedef __attribute__((ext_vector_type(4))) float f32x4;

__device__ __forceinline__ float sspf(float v) {
  return fmaxf(v, 0.0f) + __logf(1.0f + __expf(-fabsf(v))) - 0.6931471805599453f;
}

__device__ __forceinline__ short f2bf(float x) {
  union { float f; unsigned u; } v; v.f = x;
  unsigned r = v.u + 0x7fffu + ((v.u >> 16) & 1u);   // RNE
  return (short)(r >> 16);
}

#if defined(__has_builtin)
#if __has_builtin(__builtin_amdgcn_cvt_pk_bf16_f32)
#define HAS_PKBF 1
#endif
#endif

__device__ __forceinline__ unsigned pk2bf(float a, float b) {
#ifdef HAS_PKBF
  typedef __attribute__((ext_vector_type(2))) __bf16 v2bf;
  union { v2bf v; unsigned u; } c;
  c.v = __builtin_amdgcn_cvt_pk_bf16_f32(a, b);
  return c.u;
#else
  union { float f; unsigned u; } x, y; x.f = a; y.f = b;
  const unsigned ra = (x.u + 0x7fffu + ((x.u >> 16) & 1u)) >> 16;
  const unsigned rb = (y.u + 0x7fffu + ((y.u >> 16) & 1u)) & 0xffff0000u;
  return ra | rb;
#endif
}

__device__ __forceinline__ float bf2f(unsigned short us) {
  union { unsigned u; float f; } v; v.u = ((unsigned)us) << 16; return v.f;
}

__device__ __forceinline__ bf16x8 pack8(float4 a, float4 b) {
  bf16x8 r;
  unsigned* p = (unsigned*)&r;
  p[0] = pk2bf(a.x, a.y); p[1] = pk2bf(a.z, a.w);
  p[2] = pk2bf(b.x, b.y); p[3] = pk2bf(b.z, b.w);
  return r;
}

// W^T-style fragment built from row-major M[k][n]: elem i = bf16(M[k0q+i][n])
__device__ __forceinline__ bf16x8 fragT(const float* __restrict__ M, int ldn,
                                        int n, int k0q) {
  float e[8];
#pragma unroll
  for (int i = 0; i < 8; ++i) e[i] = M[(size_t)(k0q + i) * ldn + n];
  bf16x8 r; unsigned* p = (unsigned*)&r;
  p[0] = pk2bf(e[0], e[1]); p[1] = pk2bf(e[2], e[3]);
  p[2] = pk2bf(e[4], e[5]); p[3] = pk2bf(e[6], e[7]);
  return r;
}

// same but rows k >= NG read as 0 (w1 is [25][128])
__device__ __forceinline__ bf16x8 fragT25(const float* __restrict__ M,
                                          int n, int k0q) {
  float e[8];
#pragma unroll
  for (int i = 0; i < 8; ++i)
    e[i] = (k0q + i < NG) ? M[(size_t)(k0q + i) * NF + n] : 0.0f;
  bf16x8 r; unsigned* p = (unsigned*)&r;
  p[0] = pk2bf(e[0], e[1]); p[1] = pk2bf(e[2], e[3]);
  p[2] = pk2bf(e[4], e[5]); p[3] = pk2bf(e[6], e[7]);
  return r;
}

// ---- k_prep1 grid layout (all blocks independent) ----
#define B_TT 48                  // in2f transpose: 3 x 16 tiles
#define B_AT (B_TT + 192)        // aw transpose: 3 x 64 tiles           -> 240
#define B_PF (B_AT + 24)         // W12 fuse + b12                       -> 264
#define B_TAB (B_PF + 192)       // filter table direct: 3 x 64          -> 456
#define P1_TOT (B_TAB + 1024)    // neighbor compaction: 4096/4          -> 1480

// ---- k_prep2 grid layout ----
#define P2_VA 768                // vang (Gi fp32 direct, awT bf16)
#define P2_TOT (P2_VA + 256)     // + y0/x init = 1024

// ====== prep1: transposes, W12, filter table, neighbor compaction =========
__global__ __launch_bounds__(256) void k_prep1(
    const float* __restrict__ fw1, const float* __restrict__ fb1,
    const float* __restrict__ fw2, const float* __restrict__ fb2,
    const float* __restrict__ in2f, const float* __restrict__ aw,
    const float* __restrict__ f2o, const float* __restrict__ f2ob,
    const float* __restrict__ dw, const float* __restrict__ db,
    const float* __restrict__ pos, const int* __restrict__ nbr,
    const int* __restrict__ nmask,
    short* __restrict__ in2fT, short* __restrict__ awT,
    short* __restrict__ W12T, float* __restrict__ b12,
    float* __restrict__ Ttab, int4* __restrict__ ent,
    int* __restrict__ nvArr) {
  __shared__ alignas(16) short sTile[32][33];
  __shared__ alignas(16) short sH[16 * 136];
  __shared__ alignas(16) int4 sCmp[4][NN];
  const int bx = blockIdx.x;
  const int t = threadIdx.x;
  const int lane = t & 63, wave = t >> 6;
  const int lanelo = lane & 15, quad = lane >> 4;
  const int wbase = wave << 5;

  if (bx < B_AT) {
    // ---- tiled bf16 transposes: in2f -> in2fT, aw -> awT ----
    const float* src; short* dst; int tk0, tn0, stride;
    if (bx < B_TT) {
      const int l = bx >> 4, tile = bx & 15;
      src = in2f + (size_t)l * 16384;
      dst = in2fT + (size_t)l * 16384;
      tk0 = (tile >> 2) << 5; tn0 = (tile & 3) << 5; stride = 128;
    } else {
      const int ab = bx - B_TT;
      const int l = ab >> 6, tile = ab & 63;
      src = aw + (size_t)l * 65536;
      dst = awT + (size_t)l * 65536;
      tk0 = (tile >> 2) << 5; tn0 = (tile & 3) << 5; stride = 512;
    }
    const int tr = t >> 3, tc4 = (t & 7) << 2;
    const float4 v = *(const float4*)(src + (size_t)(tk0 + tr) * 128 + tn0 + tc4);
    sTile[tr][tc4] = f2bf(v.x); sTile[tr][tc4 + 1] = f2bf(v.y);
    sTile[tr][tc4 + 2] = f2bf(v.z); sTile[tr][tc4 + 3] = f2bf(v.w);
    __syncthreads();
    short o[4];
#pragma unroll
    for (int j = 0; j < 4; ++j) o[j] = sTile[tc4 + j][tr];
    uint2 pk;
    pk.x = ((unsigned)(unsigned short)o[0]) | (((unsigned)(unsigned short)o[1]) << 16);
    pk.y = ((unsigned)(unsigned short)o[2]) | (((unsigned)(unsigned short)o[3]) << 16);
    *(uint2*)(dst + (size_t)(tn0 + tr) * stride + tk0 + tc4) = pk;
    return;
  }
  if (bx < B_PF) {
    // ---- W12 = f2o@dw (bf16 [j][i]), b12 = f2ob@dw + db ----
    const int fb = bx - B_AT;
    const int l = fb >> 3, xi = fb & 7;
    const int i = (xi << 4) + lanelo;
    const float* f2o_l = f2o + (size_t)l * 16384;
    const float* dw_l = dw + (size_t)l * 16384;
    short* W12T_l = W12T + (size_t)l * 16384;
    f32x4 c[2] = {{0.f, 0.f, 0.f, 0.f}, {0.f, 0.f, 0.f, 0.f}};
#pragma unroll
    for (int kt = 0; kt < 4; ++kt) {
      const int k0 = kt * 32 + quad * 8;
      const bf16x8 b = pack8(*(const float4*)(f2o_l + (size_t)i * 128 + k0),
                             *(const float4*)(f2o_l + (size_t)i * 128 + k0 + 4));
#pragma unroll
      for (int ct = 0; ct < 2; ++ct) {
        const bf16x8 a = fragT(dw_l, 128, wbase + ct * 16 + lanelo, k0);
        c[ct] = __builtin_amdgcn_mfma_f32_16x16x32_bf16(a, b, c[ct], 0, 0, 0);
      }
    }
#pragma unroll
    for (int ct = 0; ct < 2; ++ct)
#pragma unroll
      for (int reg = 0; reg < 4; ++reg) {
        const int j = wbase + ct * 16 + quad * 4 + reg;
        W12T_l[(size_t)j * 128 + i] = f2bf(c[ct][reg]);
      }
    if (xi == 0 && t < 128) {
      float acc = db[(size_t)l * 128 + t];
      for (int k = 0; k < 128; ++k)
        acc += f2ob[(size_t)l * 128 + k] * dw_l[(size_t)k * 128 + t];
      b12[(size_t)l * 128 + t] = acc;
    }
    return;
  }
  if (bx < B_TAB) {
    // ---- filter table via MFMA, direct fp32 weight fragments ----
    const int tb = bx - B_PF;                  // 0..191
    const int l = tb >> 6;
    const int chunk = tb & 63;                 // 16-row chunk
    const float* fw1_l = fw1 + (size_t)l * NG * NF;
    const float* fw2_l = fw2 + (size_t)l * 16384;
    const float* b1 = fb1 + (size_t)l * NF;
    const float* b2 = fb2 + (size_t)l * NF;

    float4 b1v[2];
    float b2r[2];
#pragma unroll
    for (int ct = 0; ct < 2; ++ct) {
      b1v[ct] = *(const float4*)(b1 + wbase + ct * 16 + quad * 4);
      b2r[ct] = b2[wbase + ct * 16 + lanelo];
    }

    const float stepg = 3.8f / 24.0f;
    const float coef = -0.5f / (stepg * stepg);
    const float rv = (float)(chunk * 16 + lanelo) * (5.0f / 1023.0f);
    bf16x8 gb;
    {
      float e[8];
#pragma unroll
      for (int i = 0; i < 8; ++i) {
        const int g = quad * 8 + i;
        const float d = rv - (1.2f + stepg * (float)g);
        e[i] = (g < NG) ? __expf(coef * d * d) : 0.0f;
      }
      unsigned* gp = (unsigned*)&gb;
      gp[0] = pk2bf(e[0], e[1]); gp[1] = pk2bf(e[2], e[3]);
      gp[2] = pk2bf(e[4], e[5]); gp[3] = pk2bf(e[6], e[7]);
    }
    // phase 1: h = ssp(gauss @ w1 + b1) -> sH[row][f]
#pragma unroll
    for (int ct = 0; ct < 2; ++ct) {
      const bf16x8 a = fragT25(fw1_l, wbase + ct * 16 + lanelo, quad * 8);
      f32x4 c = {0.f, 0.f, 0.f, 0.f};
      c = __builtin_amdgcn_mfma_f32_16x16x32_bf16(a, gb, c, 0, 0, 0);
      const int f0 = wbase + ct * 16 + quad * 4;
      uint2 pk;
      pk.x = pk2bf(sspf(c[0] + b1v[ct].x), sspf(c[1] + b1v[ct].y));
      pk.y = pk2bf(sspf(c[2] + b1v[ct].z), sspf(c[3] + b1v[ct].w));
      *(uint2*)(sH + lanelo * 136 + f0) = pk;
    }
    __syncthreads();
    // phase 2: T = h @ w2 + b2 -> Ttab fp32
    f32x4 acc[2];
    acc[0] = (f32x4){b2r[0], b2r[0], b2r[0], b2r[0]};
    acc[1] = (f32x4){b2r[1], b2r[1], b2r[1], b2r[1]};
#pragma unroll
    for (int kt = 0; kt < 4; ++kt) {
      const bf16x8 ah = *(const bf16x8*)(sH + lanelo * 136 + kt * 32 + quad * 8);
#pragma unroll
      for (int ct = 0; ct < 2; ++ct) {
        const bf16x8 a = fragT(fw2_l, 128, wbase + ct * 16 + lanelo, kt * 32 + quad * 8);
        acc[ct] = __builtin_amdgcn_mfma_f32_16x16x32_bf16(ah, a, acc[ct], 0, 0, 0);
      }
    }
#pragma unroll
    for (int ct = 0; ct < 2; ++ct)
#pragma unroll
      for (int reg = 0; reg < 4; ++reg) {
        const int rrow = chunk * 16 + quad * 4 + reg;
        const int f = wbase + ct * 16 + lanelo;
        Ttab[((size_t)l * TABN + rrow) * NF + f] = acc[ct][reg];
      }
    return;
  }
  // ---- neighbor compaction: layer-invariant lerp entries ----
  {
    const int ga = (bx - B_TAB) * 4 + wave;    // 4 atoms/block, 1 per wave
    const int b0 = ga & ~(NA - 1);
    const int nj = nbr[(size_t)ga * NN + lane];
    const int mk = nmask[(size_t)ga * NN + lane];
    const float px = pos[(size_t)ga * 3];
    const float py = pos[(size_t)ga * 3 + 1];
    const float pz = pos[(size_t)ga * 3 + 2];
    const float* pj = pos + (size_t)(b0 + nj) * 3;
    const float dx = pj[0] - px, dy = pj[1] - py, dz = pj[2] - pz;
    const float r = sqrtf(dx * dx + dy * dy + dz * dz + 1e-12f);
    const bool valid = (r <= 5.0f) && (mk != 0);
    const unsigned long long m = __ballot(valid);
    const int posc = __popcll(m & ((1ull << lane) - 1ull));
    const float tt = r * ((float)(TABN - 1) / 5.0f);
    int k0 = (int)tt; if (k0 > TABN - 2) k0 = TABN - 2;
    const float fr = tt - (float)k0;
    sCmp[wave][lane] = make_int4(0, b0 * NF, 0, 0);          // zero entry
    if (valid)
      sCmp[wave][posc] = make_int4(k0 * NF, (b0 + nj) * NF,
                                   __float_as_int(1.0f - fr), __float_as_int(fr));
    // wave-private rows; in-wave LDS ordering suffices (no barrier)
    ent[(size_t)ga * NN + lane] = sCmp[wave][lane];
    if (lane == 0) nvArr[ga] = (int)__popcll(m);
  }
}

// ======= prep2: vang (Gi fp32 direct) + y0 (bf16 MFMA) =====================
__global__ __launch_bounds__(256) void k_prep2(
    const float* __restrict__ emb, const int* __restrict__ zn,
    const float* __restrict__ Gi, const short* __restrict__ awT,
    const short* __restrict__ in2fT,
    short* __restrict__ vangB, float* __restrict__ x, short* __restrict__ yB) {
  const int bx = blockIdx.x;
  const int t = threadIdx.x;
  const int lane = t & 63, wave = t >> 6;
  const int lanelo = lane & 15, quad = lane >> 4;
  const int wbase = wave << 5;

  if (bx < P2_VA) {
    // ---- vangB[l] = bf16(bf16(Gi) @ awT[l]) ----
    const int l = bx >> 8;
    const int row = ((bx & 255) << 4) + lanelo;
    const short* awT_l = awT + (size_t)l * 65536;
    const float* grow = Gi + (size_t)row * NGA;
    f32x4 c[2] = {{0.f, 0.f, 0.f, 0.f}, {0.f, 0.f, 0.f, 0.f}};
#pragma unroll
    for (int kt = 0; kt < 16; ++kt) {
      const int k0 = kt * 32 + quad * 8;
      const bf16x8 b = pack8(*(const float4*)(grow + k0),
                             *(const float4*)(grow + k0 + 4));
#pragma unroll
      for (int ct = 0; ct < 2; ++ct) {
        const bf16x8 a = *(const bf16x8*)(awT_l + (size_t)(wbase + ct * 16 + lanelo) * 512 + k0);
        c[ct] = __builtin_amdgcn_mfma_f32_16x16x32_bf16(a, b, c[ct], 0, 0, 0);
      }
    }
    short* vrow = vangB + ((size_t)l * NB * NA + row) * 128;
#pragma unroll
    for (int ct = 0; ct < 2; ++ct) {
      uint2 pk; pk.x = pk2bf(c[ct][0], c[ct][1]); pk.y = pk2bf(c[ct][2], c[ct][3]);
      *(uint2*)(vrow + wbase + ct * 16 + quad * 4) = pk;
    }
    return;
  }
  // ---- y0 = bf16(emb[zn] @ in2f[0]); wave 0 also writes x = emb[zn] ----
  {
    const int row = ((bx - P2_VA) << 4) + lanelo;
    const float* erow = emb + (size_t)zn[row] * ND;
    f32x4 c[2] = {{0.f, 0.f, 0.f, 0.f}, {0.f, 0.f, 0.f, 0.f}};
#pragma unroll
    for (int kt = 0; kt < 4; ++kt) {
      const int k0 = kt * 32 + quad * 8;
      const float4 e0 = *(const float4*)(erow + k0);
      const float4 e1 = *(const float4*)(erow + k0 + 4);
      if (wave == 0) {
        *(float4*)(x + (size_t)row * ND + k0) = e0;
        *(float4*)(x + (size_t)row * ND + k0 + 4) = e1;
      }
      const bf16x8 b = pack8(e0, e1);
#pragma unroll
      for (int ct = 0; ct < 2; ++ct) {
        const bf16x8 a = *(const bf16x8*)(in2fT + (size_t)(wbase + ct * 16 + lanelo) * 128 + k0);
        c[ct] = __builtin_amdgcn_mfma_f32_16x16x32_bf16(a, b, c[ct], 0, 0, 0);
      }
    }
#pragma unroll
    for (int ct = 0; ct < 2; ++ct) {
      const int c0 = wbase + ct * 16 + quad * 4;
      uint2 pk; pk.x = pk2bf(c[ct][0], c[ct][1]); pk.y = pk2bf(c[ct][2], c[ct][3]);
      *(uint2*)(yB + (size_t)row * 128 + c0) = pk;
    }
  }
}

// ====== fused layer: precompacted table-lerp conv + interaction update =====
// 512 blocks x 512 threads; block owns 8 atoms, ONE atom per wave (2 blk/CU).
// Conv: coalesced entry preload -> pure lerp loop. Update: MFMA on 16-row
// tiles (rows 8..15 garbage, never stored). y double-buffered across layers.
__global__ __launch_bounds__(512) void k_layer(
    const short* __restrict__ yIn, const float* __restrict__ Tt,
    float* __restrict__ x, const short* __restrict__ vangL,
    const short* __restrict__ W12Tl, const float* __restrict__ b12l,
    const short* __restrict__ in2fTn, short* __restrict__ yOut,
    const int4* __restrict__ ent, const int* __restrict__ nvArr) {
  __shared__ alignas(16) int4 sEnt[8][NN];
  __shared__ alignas(16) float sAgg[16][136];
  __shared__ alignas(16) short sT[16 * 136];

  const int t = threadIdx.x;
  const int lane = t & 63;
  const int wave = t >> 6;            // 0..7 = atom slot
  const int lanelo = lane & 15;
  const int quad = lane >> 4;
  const int ga0 = blockIdx.x << 3;

  // ---- coalesced entry preload (wave-private rows: no barrier needed) ----
  sEnt[wave][lane] = ent[(size_t)(ga0 + wave) * NN + lane];
  const int nv = nvArr[ga0 + wave];

  const unsigned short* yu = (const unsigned short*)yIn;
  float acc0 = 0.f, acc1 = 0.f;
  const int ntc = (nv + 3) & ~3;
  for (int c = 0; c < ntc; c += 4) {
#pragma unroll
    for (int u = 0; u < 4; ++u) {
      const int4 e = sEnt[wave][c + u];
      const float w0 = __int_as_float(e.z), w1 = __int_as_float(e.w);
      const float t0a = Tt[e.x + lane];
      const float t0b = Tt[e.x + lane + 64];
      const float t1a = Tt[e.x + NF + lane];
      const float t1b = Tt[e.x + NF + lane + 64];
      const float wva = fmaf(w0, t0a, w1 * t1a);
      const float wvb = fmaf(w0, t0b, w1 * t1b);
      acc0 = fmaf(wva, bf2f(yu[e.y + lane]), acc0);
      acc1 = fmaf(wvb, bf2f(yu[e.y + lane + 64]), acc1);
    }
  }
  sAgg[wave][lane] = acc0;
  sAgg[wave][lane + 64] = acc1;
  __syncthreads();

  // ---- update GEMM 1: v2 = W12 @ agg (8 atoms in cols 0..7) ----
  f32x4 c2 = {0.f, 0.f, 0.f, 0.f};
#pragma unroll
  for (int kt = 0; kt < 4; ++kt) {
    const float* ar = &sAgg[lanelo][kt * 32 + quad * 8];
    const bf16x8 b = pack8(*(const float4*)ar, *(const float4*)(ar + 4));
    const bf16x8 a = *(const bf16x8*)(W12Tl + ((wave << 4) + lanelo) * 128 + kt * 32 + quad * 8);
    c2 = __builtin_amdgcn_mfma_f32_16x16x32_bf16(a, b, c2, 0, 0, 0);
  }

  const int c0 = (wave << 4) + quad * 4;
  const int row = ga0 + lanelo;
  if (lanelo < 8) {
    const float4 dv = *(const float4*)(b12l + c0);
    const unsigned short* vp = (const unsigned short*)(vangL + (size_t)row * 128 + c0);
    float* xp = x + (size_t)row * 128 + c0;
    const float4 xv = *(const float4*)xp;
    float4 xo;
    xo.x = xv.x + sspf(c2[0] + bf2f(vp[0]) + dv.x);
    xo.y = xv.y + sspf(c2[1] + bf2f(vp[1]) + dv.y);
    xo.z = xv.z + sspf(c2[2] + bf2f(vp[2]) + dv.z);
    xo.w = xv.w + sspf(c2[3] + bf2f(vp[3]) + dv.w);
    *(float4*)xp = xo;
    if (in2fTn != nullptr) {
      uint2 pk; pk.x = pk2bf(xo.x, xo.y); pk.y = pk2bf(xo.z, xo.w);
      *(uint2*)(sT + lanelo * 136 + c0) = pk;
    }
  }
  if (in2fTn == nullptr) return;
  __syncthreads();

  // ---- update GEMM 2: y_next = in2f[l+1] @ x_new ----
  f32x4 c3 = {0.f, 0.f, 0.f, 0.f};
#pragma unroll
  for (int kt = 0; kt < 4; ++kt) {
    const bf16x8 b = *(const bf16x8*)(sT + lanelo * 136 + kt * 32 + quad * 8);
    const bf16x8 a = *(const bf16x8*)(in2fTn + ((wave << 4) + lanelo) * 128 + kt * 32 + quad * 8);
    c3 = __builtin_amdgcn_mfma_f32_16x16x32_bf16(a, b, c3, 0, 0, 0);
  }
  if (lanelo < 8) {
    uint2 pk; pk.x = pk2bf(c3[0], c3[1]); pk.y = pk2bf(c3[2], c3[3]);
    *(uint2*)(yOut + (size_t)row * 128 + c0) = pk;
  }
}

extern "C" void kernel_launch(void* const* d_in, const int* in_sizes, int n_in,
                              void* d_out, int out_size, void* d_ws, size_t ws_size,
                              hipStream_t stream) {
  (void)in_sizes; (void)n_in; (void)out_size; (void)ws_size;
  const int* zn = (const int*)d_in[0];
  const float* pos = (const float*)d_in[1];
  const int* nbr = (const int*)d_in[2];
  const int* nmask = (const int*)d_in[3];
  const float* Gi = (const float*)d_in[4];
  const float* emb = (const float*)d_in[5];
  const float* fw1 = (const float*)d_in[6];
  const float* fb1 = (const float*)d_in[7];
  const float* fw2 = (const float*)d_in[8];
  const float* fb2 = (const float*)d_in[9];
  const float* in2f = (const float*)d_in[10];
  const float* f2o = (const float*)d_in[11];
  const float* f2ob = (const float*)d_in[12];
  const float* dwp = (const float*)d_in[13];
  const float* dbp = (const float*)d_in[14];
  const float* awp = (const float*)d_in[15];

  float* x = (float*)d_out;                              // [B,A,D] fp32
  float* b12 = (float*)d_ws;                             // [3][128] fp32
  float* Ttab = b12 + 3 * 128;                           // [3][1024][128] fp32
  short* vangB = (short*)(Ttab + (size_t)3 * TABN * NF); // [3][B*A][128] bf16
  short* yA = vangB + (size_t)3 * NB * NA * ND;          // y buf 0
  short* yBb = yA + (size_t)NB * NA * NF;                // y buf 1
  short* in2fT = yBb + (size_t)NB * NA * NF;             // [3][128][128]
  short* W12T = in2fT + (size_t)3 * 128 * 128;           // [3][128][128]
  short* awT = W12T + (size_t)3 * 128 * 128;             // [3][128][512]
  int4* ent = (int4*)(awT + (size_t)3 * 128 * 512);      // [B*A][64]
  int* nvArr = (int*)(ent + (size_t)NB * NA * NN);       // [B*A]

  k_prep1<<<P1_TOT, 256, 0, stream>>>(
      fw1, fb1, fw2, fb2, in2f, awp, f2o, f2ob, dwp, dbp,
      pos, nbr, nmask,
      in2fT, awT, W12T, b12, Ttab, ent, nvArr);
  k_prep2<<<P2_TOT, 256, 0, stream>>>(
      emb, zn, Gi, awT, in2fT, vangB, x, yA);

  short* yin = yA;
  short* yout = yBb;
  for (int l = 0; l < 3; ++l) {
    k_layer<<<NB * NA / 8, 512, 0, stream>>>(yin,
        Ttab + (size_t)l * TABN * NF,
        x, vangB + (size_t)l * NB * NA * ND,
        W12T + (size_t)l * 16384, b12 + (size_t)l * 128,
        (l < 2) ? (in2fT + (size_t)(l + 1) * 16384) : nullptr, yout,
        ent, nvArr);
    short* tmp = yin; yin = yout; yout = tmp;
  }
}